// Round 10
// baseline (2305.373 us; speedup 1.0000x reference)
//
#include <hip/hip_runtime.h>

#define BATCH 2048
#define NNEI 64
#define IN_DIM 80
#define EMBED 256
#define NCLS 5
#define NMODES 20
#define NROWS (BATCH * NNEI)   // 131072
#define NEXP (NCLS + 1)        // 6 neighbor experts
#define TM 16                  // rows per MFMA tile
#define GRID2 512              // persistent blocks for nei_gemv (2/CU)
#define MAXT 104               // max tiles per block

#define NBIN (NROWS / 256)     // 512 bin blocks
#define NWF 144                // wfrag blocks (4 frags each, 576 total)
#define NPRJ (NCLS * NMODES)   // 100 proj blocks

typedef __attribute__((ext_vector_type(8))) short bf16x8;
typedef __attribute__((ext_vector_type(4))) float f32x4;
typedef __attribute__((ext_vector_type(4))) int i32x4;

__device__ inline unsigned short bf16_rne(float f) {
    unsigned u = __builtin_bit_cast(unsigned, f);
    unsigned r = (u + 0x7fffu + ((u >> 16) & 1u)) >> 16;
    return (unsigned short)r;
}
__device__ inline float bf16_to_f(unsigned short h) {
    unsigned u = ((unsigned)h) << 16;
    return __builtin_bit_cast(float, u);
}

// ---------------- K1: fused prep — bin | wfrag | proj by blockIdx range ----
__global__ void prep_all(const int* __restrict__ nei_labels,
                         int* __restrict__ counts, int* __restrict__ lists,
                         const float* __restrict__ nei_W, unsigned short* __restrict__ wfrag,
                         const float* __restrict__ modes, const float* __restrict__ mode_W,
                         const float* __restrict__ mode_b, float* __restrict__ proj) {
    __shared__ int lc[NEXP], lb[NEXP];
    const int b = blockIdx.x;
    const int t = threadIdx.x;

    if (b < NBIN) {
        if (t < NEXP) lc[t] = 0;
        __syncthreads();
        int r = b * 256 + t;
        int c = nei_labels[r];
        int lpos = atomicAdd(&lc[c], 1);
        __syncthreads();
        if (t < NEXP) lb[t] = atomicAdd(&counts[t], lc[t]);
        __syncthreads();
        lists[(size_t)c * NROWS + lb[c] + lpos] = r;
    } else if (b < NBIN + NWF) {
        int e = (b - NBIN) * 4 + (t >> 6);    // 0..575
        int l = t & 63;
        int part = e & 1;
        int cfg = (e >> 1) & 15;
        int ks = (e >> 5) % 3;
        int c = e / 96;
        int col = cfg * 16 + (l & 15);
        unsigned short v[8] __attribute__((aligned(16)));
        #pragma unroll
        for (int j = 0; j < 8; ++j) {
            int k = ks * 32 + ((l >> 4) * 8) + j;
            float w = (k < IN_DIM) ? nei_W[((size_t)c * IN_DIM + k) * EMBED + col] : 0.f;
            unsigned short h = bf16_rne(w);
            if (part == 0) v[j] = h;
            else v[j] = bf16_rne(w - bf16_to_f(h));
        }
        unsigned short* dst = wfrag + ((size_t)e * 64 + l) * 8;
        *reinterpret_cast<i32x4*>(dst) = *reinterpret_cast<const i32x4*>(v);
    } else {
        int cm = b - (NBIN + NWF);            // 0..99
        int o = t;
        const float* mv = modes + (size_t)cm * EMBED;
        float acc = mode_b[o];
        #pragma unroll 8
        for (int k = 0; k < EMBED; ++k)
            acc = fmaf(mv[k], mode_W[(size_t)(EMBED + k) * EMBED + o], acc);
        proj[(size_t)cm * EMBED + o] = acc;
    }
}

// ---------------- K2: obs embedding + mode head (templated reps) ----------------
#define BPB 4
template<int REPS>
__global__ __launch_bounds__(256, 2)
void obs_t(const float* __restrict__ obs, const int* __restrict__ self_labels,
           const float* __restrict__ obs_W, const float* __restrict__ obs_b,
           const float* __restrict__ mode_W, const float* __restrict__ proj,
           float* __restrict__ out0) {
    int b0 = blockIdx.x * BPB;
    int o = threadIdx.x;
    __shared__ float obs_s[BPB][IN_DIM];
    __shared__ float x_s[BPB][EMBED];
    __shared__ int cls_s[BPB];

    for (int rep = 0; rep < REPS; ++rep) {
        for (int t = threadIdx.x; t < BPB * IN_DIM; t += 256) {
            int bb = t / IN_DIM, k = t % IN_DIM;
            obs_s[bb][k] = obs[(size_t)(b0 + bb) * IN_DIM + k];
        }
        if (threadIdx.x < BPB) cls_s[threadIdx.x] = self_labels[b0 + threadIdx.x];
        __syncthreads();

        int c[BPB];
        float xacc[BPB];
        #pragma unroll
        for (int bb = 0; bb < BPB; ++bb) {
            c[bb] = cls_s[bb];
            xacc[bb] = obs_b[c[bb] * EMBED + o];
        }
        #pragma unroll 4
        for (int k = 0; k < IN_DIM; ++k) {
            #pragma unroll
            for (int bb = 0; bb < BPB; ++bb)
                xacc[bb] = fmaf(obs_s[bb][k],
                                obs_W[(size_t)c[bb] * IN_DIM * EMBED + (size_t)k * EMBED + o],
                                xacc[bb]);
        }
        #pragma unroll
        for (int bb = 0; bb < BPB; ++bb) x_s[bb][o] = xacc[bb];
        __syncthreads();

        float tacc[BPB];
        #pragma unroll
        for (int bb = 0; bb < BPB; ++bb) tacc[bb] = 0.f;
        #pragma unroll 4
        for (int k = 0; k < EMBED; ++k) {
            float wv = mode_W[(size_t)k * EMBED + o];
            #pragma unroll
            for (int bb = 0; bb < BPB; ++bb)
                tacc[bb] = fmaf(x_s[bb][k], wv, tacc[bb]);
        }
        #pragma unroll
        for (int bb = 0; bb < BPB; ++bb) {
            const float* pj = proj + (size_t)c[bb] * NMODES * EMBED;
            float* op = out0 + (size_t)(b0 + bb) * NMODES * EMBED;
            for (int m = 0; m < NMODES; ++m)
                op[m * EMBED + o] = tacc[bb] + pj[m * EMBED + o];
        }
        __syncthreads();
    }
}

// ---------------- K3: MFMA neighbor GEMM (templated ablation) ----------------
template<int LOAD, int MFMA, int STORE, int REPS>
__global__ __launch_bounds__(256, 2)
void gemv_t(const float* __restrict__ neis,
            const unsigned short* __restrict__ wfrag,
            const float* __restrict__ nei_b,
            const int* __restrict__ counts,
            const int* __restrict__ lists,
            float* __restrict__ dst) {
    const int b = blockIdx.x;
    const int c = (b * NEXP) / GRID2;
    const int cstart = (c * GRID2 + NEXP - 1) / NEXP;
    const int cend = ((c + 1) * GRID2 + NEXP - 1) / NEXP;
    const int blk = b - cstart;
    const int nblk = cend - cstart;
    const int cnt = counts[c];
    const int ntiles = (cnt + TM - 1) / TM;

    __shared__ int rids_s[MAXT * TM];

    if (blk >= ntiles || cnt == 0) return;
    const int nt = min((ntiles - blk + nblk - 1) / nblk, MAXT);

    const int ch = threadIdx.x >> 6;
    const int l = threadIdx.x & 63;
    const int* mylist = lists + (size_t)c * NROWS;
    const int kc = (l >> 4) * 8;

    for (int i = threadIdx.x; i < nt * TM; i += 256) {
        int j = i >> 4, r = i & 15;
        int gi = (blk + j * nblk) * TM + r;
        rids_s[i] = mylist[min(gi, cnt - 1)];
    }

    bf16x8 wh[3][4], wl[3][4];
    {
        const unsigned short* wb = wfrag + (size_t)c * 96 * 64 * 8;
        #pragma unroll
        for (int ks = 0; ks < 3; ++ks)
            #pragma unroll
            for (int cf = 0; cf < 4; ++cf) {
                size_t base = ((((size_t)ks * 16 + (ch * 4 + cf)) * 2) * 64 + l) * 8;
                wh[ks][cf] = *reinterpret_cast<const bf16x8*>(wb + base);
                wl[ks][cf] = *reinterpret_cast<const bf16x8*>(wb + base + 64 * 8);
            }
    }
    #pragma unroll
    for (int ks = 0; ks < 3; ++ks)
        #pragma unroll
        for (int cf = 0; cf < 4; ++cf) {
            i32x4 th = __builtin_bit_cast(i32x4, wh[ks][cf]);
            asm volatile("" : "+v"(th));
            wh[ks][cf] = __builtin_bit_cast(bf16x8, th);
            i32x4 tl = __builtin_bit_cast(i32x4, wl[ks][cf]);
            asm volatile("" : "+v"(tl));
            wl[ks][cf] = __builtin_bit_cast(bf16x8, tl);
        }
    float bias[4];
    #pragma unroll
    for (int cf = 0; cf < 4; ++cf) {
        bias[cf] = nei_b[c * EMBED + (ch * 4 + cf) * 16 + (l & 15)];
        asm volatile("" : "+v"(bias[cf]));
    }
    __syncthreads();

#define LOADJ(F, R, J) {                                                      \
    R = rids_s[(J) * TM + (l & 15)];                                          \
    if constexpr (LOAD) {                                                     \
        const float* bp_ = neis + (size_t)(unsigned)R * IN_DIM;               \
        _Pragma("unroll")                                                     \
        for (int ks_ = 0; ks_ < 3; ++ks_) {                                   \
            int k0_ = ks_ * 32 + kc;                                          \
            if (k0_ + 8 > IN_DIM) k0_ = 0;                                    \
            *reinterpret_cast<float4*>(&F[ks_ * 8])     = *reinterpret_cast<const float4*>(bp_ + k0_);     \
            *reinterpret_cast<float4*>(&F[ks_ * 8 + 4]) = *reinterpret_cast<const float4*>(bp_ + k0_ + 4); \
        }                                                                     \
    } else {                                                                  \
        _Pragma("unroll")                                                     \
        for (int j_ = 0; j_ < 24; ++j_)                                       \
            F[j_] = 0.75f + 0.001f * (float)(l + j_);                         \
    } }

#define COMPJ(F, R, J) {                                                      \
    bf16x8 ah_[3], al_[3];                                                    \
    _Pragma("unroll")                                                         \
    for (int ks_ = 0; ks_ < 3; ++ks_) {                                       \
        _Pragma("unroll")                                                     \
        for (int j_ = 0; j_ < 8; ++j_) {                                      \
            float v_ = F[ks_ * 8 + j_];                                       \
            float d_ = (v_ >= 0.f) ? (v_ + 1e-4f) : (v_ - 1e-4f);             \
            float r_ = __builtin_amdgcn_rcpf(d_);                             \
            unsigned short hi_ = bf16_rne(r_);                                \
            ah_[ks_][j_] = (short)hi_;                                        \
            al_[ks_][j_] = (short)bf16_rne(r_ - bf16_to_f(hi_));              \
        }                                                                     \
    }                                                                         \
    f32x4 acc_[4];                                                            \
    _Pragma("unroll")                                                         \
    for (int cf_ = 0; cf_ < 4; ++cf_) acc_[cf_] = (f32x4){0.f, 0.f, 0.f, 0.f};\
    if constexpr (MFMA) {                                                     \
        _Pragma("unroll")                                                     \
        for (int ks_ = 0; ks_ < 3; ++ks_) {                                   \
            _Pragma("unroll")                                                 \
            for (int cf_ = 0; cf_ < 4; ++cf_) {                               \
                acc_[cf_] = __builtin_amdgcn_mfma_f32_16x16x32_bf16(ah_[ks_], wh[ks_][cf_], acc_[cf_], 0, 0, 0); \
                acc_[cf_] = __builtin_amdgcn_mfma_f32_16x16x32_bf16(al_[ks_], wh[ks_][cf_], acc_[cf_], 0, 0, 0); \
                acc_[cf_] = __builtin_amdgcn_mfma_f32_16x16x32_bf16(ah_[ks_], wl[ks_][cf_], acc_[cf_], 0, 0, 0); \
            }                                                                 \
        }                                                                     \
    } else {                                                                  \
        _Pragma("unroll")                                                     \
        for (int cf_ = 0; cf_ < 4; ++cf_)                                     \
            _Pragma("unroll")                                                 \
            for (int i_ = 0; i_ < 4; ++i_)                                    \
                acc_[cf_][i_] = bf16_to_f((unsigned short)ah_[cf_ % 3][2 * i_]) \
                              + bf16_to_f((unsigned short)al_[cf_ % 3][2 * i_ + 1]); \
    }                                                                         \
    if constexpr (STORE) {                                                    \
        int rb_ = (l >> 4) * 4;                                               \
        int tbase_ = (blk + (J) * nblk) * TM;                                 \
        _Pragma("unroll")                                                     \
        for (int i_ = 0; i_ < 4; ++i_) {                                      \
            int rid_ = __shfl(R, rb_ + i_);                                   \
            if (tbase_ + rb_ + i_ < cnt) {                                    \
                float* op_ = dst + (size_t)(unsigned)rid_ * EMBED + (l & 15); \
                _Pragma("unroll")                                             \
                for (int cf_ = 0; cf_ < 4; ++cf_)                             \
                    op_[(ch * 4 + cf_) * 16] = acc_[cf_][i_] + bias[cf_];     \
            }                                                                 \
        }                                                                     \
    } else {                                                                  \
        asm volatile("" :: "v"(acc_[0]), "v"(acc_[1]), "v"(acc_[2]), "v"(acc_[3])); \
    } }

    for (int rep = 0; rep < REPS; ++rep) {
        float fA[24], fB[24], fC[24];
        int ridA, ridB, ridC;
        LOADJ(fA, ridA, 0)
        if (nt > 1) LOADJ(fB, ridB, 1)
        int j = 0;
        while (true) {
            if (j + 2 < nt) LOADJ(fC, ridC, j + 2)
            COMPJ(fA, ridA, j)
            if (j + 1 >= nt) break;
            if (j + 3 < nt) LOADJ(fA, ridA, j + 3)
            COMPJ(fB, ridB, j + 1)
            if (j + 2 >= nt) break;
            if (j + 4 < nt) LOADJ(fB, ridB, j + 4)
            COMPJ(fC, ridC, j + 2)
            if (j + 3 >= nt) break;
            j += 3;
        }
    }
#undef LOADJ
#undef COMPJ
}

extern "C" void kernel_launch(void* const* d_in, const int* in_sizes, int n_in,
                              void* d_out, int out_size, void* d_ws, size_t ws_size,
                              hipStream_t stream) {
    const float* obs         = (const float*)d_in[0];
    const float* neis        = (const float*)d_in[1];
    const int*   self_labels = (const int*)d_in[2];
    const int*   nei_labels  = (const int*)d_in[3];
    const float* modes       = (const float*)d_in[4];
    const float* obs_W       = (const float*)d_in[5];
    const float* obs_b       = (const float*)d_in[6];
    const float* nei_W       = (const float*)d_in[7];
    const float* nei_b       = (const float*)d_in[8];
    const float* mode_W      = (const float*)d_in[9];
    const float* mode_b      = (const float*)d_in[10];

    float* out0  = (float*)d_out;
    float* out_n = out0 + (size_t)BATCH * NMODES * EMBED;

    char* ws = (char*)d_ws;
    int* counts = (int*)ws;                                        // 24 B
    int* lists  = (int*)(ws + 256);                                // 3 MiB
    float* proj = (float*)(ws + 256 + (size_t)NEXP * NROWS * 4);   // 100 KiB
    unsigned short* wfrag = (unsigned short*)(ws + 256 + (size_t)NEXP * NROWS * 4
                                              + (size_t)NCLS * NMODES * EMBED * 4); // 576 KiB
    float* dummy = (float*)(ws + (8u << 20));                      // 134 MB scratch for ablations

    hipMemsetAsync(counts, 0, NEXP * sizeof(int), stream);

    // ---- production pipeline (unchanged from round 9) ----
    prep_all<<<NBIN + NWF + NPRJ, 256, 0, stream>>>(nei_labels, counts, lists,
                                                    nei_W, wfrag,
                                                    modes, mode_W, mode_b, proj);
    obs_t<1><<<BATCH / BPB, 256, 0, stream>>>(obs, self_labels, obs_W, obs_b,
                                              mode_W, proj, out0);
    gemv_t<1, 1, 1, 1><<<GRID2, 256, 0, stream>>>(neis, wfrag, nei_b,
                                                  counts, lists, out_n);

    // ---- diagnostic replicas (idempotent / scratch-targeted; read dur/REPS) ----
    gemv_t<1, 1, 1, 8><<<GRID2, 256, 0, stream>>>(neis, wfrag, nei_b,
                                                  counts, lists, out_n);
    gemv_t<0, 1, 1, 16><<<GRID2, 256, 0, stream>>>(neis, wfrag, nei_b,
                                                   counts, lists, dummy);
    gemv_t<1, 1, 0, 16><<<GRID2, 256, 0, stream>>>(neis, wfrag, nei_b,
                                                   counts, lists, dummy);
    gemv_t<1, 0, 1, 16><<<GRID2, 256, 0, stream>>>(neis, wfrag, nei_b,
                                                   counts, lists, dummy);
    obs_t<24><<<BATCH / BPB, 256, 0, stream>>>(obs, self_labels, obs_W, obs_b,
                                               mode_W, proj, out0);
}

// Round 11
// 96.159 us; speedup vs baseline: 23.9745x; 23.9745x over previous
//
#include <hip/hip_runtime.h>

#define BATCH 2048
#define NNEI 64
#define IN_DIM 80
#define EMBED 256
#define NCLS 5
#define NMODES 20
#define NROWS (BATCH * NNEI)   // 131072
#define NEXP (NCLS + 1)        // 6 neighbor experts
#define TM 16                  // rows per MFMA tile
#define GRID2 512              // persistent blocks for nei_gemv (2/CU)
#define MAXT 104               // max tiles per block

#define NBIN (NROWS / 256)     // 512 bin blocks
#define NWF 144                // wfrag blocks (4 frags each, 576 total)
#define NPRJ (NCLS * NMODES)   // 100 proj blocks

typedef __attribute__((ext_vector_type(8))) short bf16x8;
typedef __attribute__((ext_vector_type(4))) float f32x4;
typedef __attribute__((ext_vector_type(4))) int i32x4;

__device__ inline unsigned short bf16_rne(float f) {
    unsigned u = __builtin_bit_cast(unsigned, f);
    unsigned r = (u + 0x7fffu + ((u >> 16) & 1u)) >> 16;
    return (unsigned short)r;
}
__device__ inline float bf16_to_f(unsigned short h) {
    unsigned u = ((unsigned)h) << 16;
    return __builtin_bit_cast(float, u);
}
__device__ inline void st_nt(float* p, float v) { __builtin_nontemporal_store(v, p); }

// ---------------- K1: fused prep — bin | wfrag | proj by blockIdx range ----
__global__ void prep_all(const int* __restrict__ nei_labels,
                         int* __restrict__ counts, int* __restrict__ lists,
                         const float* __restrict__ nei_W, unsigned short* __restrict__ wfrag,
                         const float* __restrict__ modes, const float* __restrict__ mode_W,
                         const float* __restrict__ mode_b, float* __restrict__ proj) {
    __shared__ int lc[NEXP], lb[NEXP];
    const int b = blockIdx.x;
    const int t = threadIdx.x;

    if (b < NBIN) {
        if (t < NEXP) lc[t] = 0;
        __syncthreads();
        int r = b * 256 + t;
        int c = nei_labels[r];
        int lpos = atomicAdd(&lc[c], 1);
        __syncthreads();
        if (t < NEXP) lb[t] = atomicAdd(&counts[t], lc[t]);
        __syncthreads();
        lists[(size_t)c * NROWS + lb[c] + lpos] = r;
    } else if (b < NBIN + NWF) {
        int e = (b - NBIN) * 4 + (t >> 6);    // 0..575
        int l = t & 63;
        int part = e & 1;
        int cfg = (e >> 1) & 15;
        int ks = (e >> 5) % 3;
        int c = e / 96;
        int col = cfg * 16 + (l & 15);
        unsigned short v[8] __attribute__((aligned(16)));
        #pragma unroll
        for (int j = 0; j < 8; ++j) {
            int k = ks * 32 + ((l >> 4) * 8) + j;
            float w = (k < IN_DIM) ? nei_W[((size_t)c * IN_DIM + k) * EMBED + col] : 0.f;
            unsigned short h = bf16_rne(w);
            if (part == 0) v[j] = h;
            else v[j] = bf16_rne(w - bf16_to_f(h));
        }
        unsigned short* dst = wfrag + ((size_t)e * 64 + l) * 8;
        *reinterpret_cast<i32x4*>(dst) = *reinterpret_cast<const i32x4*>(v);
    } else {
        int cm = b - (NBIN + NWF);            // 0..99
        int o = t;
        const float* mv = modes + (size_t)cm * EMBED;
        float acc = mode_b[o];
        #pragma unroll 8
        for (int k = 0; k < EMBED; ++k)
            acc = fmaf(mv[k], mode_W[(size_t)(EMBED + k) * EMBED + o], acc);
        proj[(size_t)cm * EMBED + o] = acc;
    }
}

// ---------------- K2: obs embedding + mode head — 4 blocks/CU for TLP ----------
#define BPB 2
__global__ __launch_bounds__(256, 4)
void obs_mode(const float* __restrict__ obs, const int* __restrict__ self_labels,
              const float* __restrict__ obs_W, const float* __restrict__ obs_b,
              const float* __restrict__ mode_W, const float* __restrict__ proj,
              float* __restrict__ out0) {
    int b0 = blockIdx.x * BPB;
    int o = threadIdx.x;
    __shared__ float obs_s[BPB][IN_DIM];
    __shared__ float x_s[BPB][EMBED];
    __shared__ int cls_s[BPB];

    for (int t = threadIdx.x; t < BPB * IN_DIM; t += 256) {
        int bb = t / IN_DIM, k = t % IN_DIM;
        obs_s[bb][k] = obs[(size_t)(b0 + bb) * IN_DIM + k];
    }
    if (threadIdx.x < BPB) cls_s[threadIdx.x] = self_labels[b0 + threadIdx.x];
    __syncthreads();

    int c[BPB];
    float xacc[BPB];
    #pragma unroll
    for (int bb = 0; bb < BPB; ++bb) {
        c[bb] = cls_s[bb];
        xacc[bb] = obs_b[c[bb] * EMBED + o];
    }
    #pragma unroll 4
    for (int k = 0; k < IN_DIM; ++k) {
        #pragma unroll
        for (int bb = 0; bb < BPB; ++bb)
            xacc[bb] = fmaf(obs_s[bb][k],
                            obs_W[(size_t)c[bb] * IN_DIM * EMBED + (size_t)k * EMBED + o],
                            xacc[bb]);
    }
    #pragma unroll
    for (int bb = 0; bb < BPB; ++bb) x_s[bb][o] = xacc[bb];
    __syncthreads();

    float tacc[BPB];
    #pragma unroll
    for (int bb = 0; bb < BPB; ++bb) tacc[bb] = 0.f;
    #pragma unroll 4
    for (int k = 0; k < EMBED; ++k) {
        float wv = mode_W[(size_t)k * EMBED + o];
        #pragma unroll
        for (int bb = 0; bb < BPB; ++bb)
            tacc[bb] = fmaf(x_s[bb][k], wv, tacc[bb]);
    }
    #pragma unroll
    for (int bb = 0; bb < BPB; ++bb) {
        const float* pj = proj + (size_t)c[bb] * NMODES * EMBED;
        float* op = out0 + (size_t)(b0 + bb) * NMODES * EMBED;
        for (int m = 0; m < NMODES; ++m)
            st_nt(&op[m * EMBED + o], tacc[bb] + pj[m * EMBED + o]);
    }
}

// ---------------- K3: MFMA neighbor GEMM — rowid LDS cache, depth-2 prefetch,
//                  pinned weights, non-temporal stores ----------------
__global__ __launch_bounds__(256, 2)
void nei_gemv_mfma(const float* __restrict__ neis,
                   const unsigned short* __restrict__ wfrag,
                   const float* __restrict__ nei_b,
                   const int* __restrict__ counts,
                   const int* __restrict__ lists,
                   float* __restrict__ out_n) {
    const int b = blockIdx.x;
    const int c = (b * NEXP) / GRID2;                    // contiguous class ranges
    const int cstart = (c * GRID2 + NEXP - 1) / NEXP;
    const int cend = ((c + 1) * GRID2 + NEXP - 1) / NEXP;
    const int blk = b - cstart;
    const int nblk = cend - cstart;
    const int cnt = counts[c];
    const int ntiles = (cnt + TM - 1) / TM;

    __shared__ int rids_s[MAXT * TM];

    if (blk >= ntiles || cnt == 0) return;
    const int nt = min((ntiles - blk + nblk - 1) / nblk, MAXT);

    const int ch = threadIdx.x >> 6;   // wave id = col-quarter 0..3
    const int l = threadIdx.x & 63;
    const int* mylist = lists + (size_t)c * NROWS;
    const int kc = (l >> 4) * 8;

    for (int i = threadIdx.x; i < nt * TM; i += 256) {
        int j = i >> 4, r = i & 15;
        int gi = (blk + j * nblk) * TM + r;
        rids_s[i] = mylist[min(gi, cnt - 1)];
    }

    bf16x8 wh[3][4], wl[3][4];
    {
        const unsigned short* wb = wfrag + (size_t)c * 96 * 64 * 8;
        #pragma unroll
        for (int ks = 0; ks < 3; ++ks)
            #pragma unroll
            for (int cf = 0; cf < 4; ++cf) {
                size_t base = ((((size_t)ks * 16 + (ch * 4 + cf)) * 2) * 64 + l) * 8;
                wh[ks][cf] = *reinterpret_cast<const bf16x8*>(wb + base);
                wl[ks][cf] = *reinterpret_cast<const bf16x8*>(wb + base + 64 * 8);
            }
    }
    #pragma unroll
    for (int ks = 0; ks < 3; ++ks)
        #pragma unroll
        for (int cf = 0; cf < 4; ++cf) {
            i32x4 th = __builtin_bit_cast(i32x4, wh[ks][cf]);
            asm volatile("" : "+v"(th));
            wh[ks][cf] = __builtin_bit_cast(bf16x8, th);
            i32x4 tl = __builtin_bit_cast(i32x4, wl[ks][cf]);
            asm volatile("" : "+v"(tl));
            wl[ks][cf] = __builtin_bit_cast(bf16x8, tl);
        }
    float bias[4];
    #pragma unroll
    for (int cf = 0; cf < 4; ++cf) {
        bias[cf] = nei_b[c * EMBED + (ch * 4 + cf) * 16 + (l & 15)];
        asm volatile("" : "+v"(bias[cf]));
    }
    __syncthreads();

#define LOADJ(F, R, J) {                                                      \
    R = rids_s[(J) * TM + (l & 15)];                                          \
    const float* bp_ = neis + (size_t)(unsigned)R * IN_DIM;                   \
    _Pragma("unroll")                                                         \
    for (int ks_ = 0; ks_ < 3; ++ks_) {                                       \
        int k0_ = ks_ * 32 + kc;                                              \
        if (k0_ + 8 > IN_DIM) k0_ = 0; /* B frag is zero for k>=80 */         \
        *reinterpret_cast<float4*>(&F[ks_ * 8])     = *reinterpret_cast<const float4*>(bp_ + k0_);     \
        *reinterpret_cast<float4*>(&F[ks_ * 8 + 4]) = *reinterpret_cast<const float4*>(bp_ + k0_ + 4); \
    } }

#define COMPJ(F, R, J) {                                                      \
    bf16x8 ah_[3], al_[3];                                                    \
    _Pragma("unroll")                                                         \
    for (int ks_ = 0; ks_ < 3; ++ks_) {                                       \
        _Pragma("unroll")                                                     \
        for (int j_ = 0; j_ < 8; ++j_) {                                      \
            float v_ = F[ks_ * 8 + j_];                                       \
            float d_ = (v_ >= 0.f) ? (v_ + 1e-4f) : (v_ - 1e-4f);             \
            float r_ = __builtin_amdgcn_rcpf(d_);                             \
            unsigned short hi_ = bf16_rne(r_);                                \
            ah_[ks_][j_] = (short)hi_;                                        \
            al_[ks_][j_] = (short)bf16_rne(r_ - bf16_to_f(hi_));              \
        }                                                                     \
    }                                                                         \
    f32x4 acc_[4];                                                            \
    _Pragma("unroll")                                                         \
    for (int cf_ = 0; cf_ < 4; ++cf_) acc_[cf_] = (f32x4){0.f, 0.f, 0.f, 0.f};\
    _Pragma("unroll")                                                         \
    for (int ks_ = 0; ks_ < 3; ++ks_) {                                       \
        _Pragma("unroll")                                                     \
        for (int cf_ = 0; cf_ < 4; ++cf_) {                                   \
            acc_[cf_] = __builtin_amdgcn_mfma_f32_16x16x32_bf16(ah_[ks_], wh[ks_][cf_], acc_[cf_], 0, 0, 0); \
            acc_[cf_] = __builtin_amdgcn_mfma_f32_16x16x32_bf16(al_[ks_], wh[ks_][cf_], acc_[cf_], 0, 0, 0); \
            acc_[cf_] = __builtin_amdgcn_mfma_f32_16x16x32_bf16(ah_[ks_], wl[ks_][cf_], acc_[cf_], 0, 0, 0); \
        }                                                                     \
    }                                                                         \
    int rb_ = (l >> 4) * 4;                                                   \
    int tbase_ = (blk + (J) * nblk) * TM;                                     \
    _Pragma("unroll")                                                         \
    for (int i_ = 0; i_ < 4; ++i_) {                                          \
        int rid_ = __shfl(R, rb_ + i_);                                       \
        if (tbase_ + rb_ + i_ < cnt) {                                        \
            float* op_ = out_n + (size_t)(unsigned)rid_ * EMBED + (l & 15);   \
            _Pragma("unroll")                                                 \
            for (int cf_ = 0; cf_ < 4; ++cf_)                                 \
                st_nt(&op_[(ch * 4 + cf_) * 16], acc_[cf_][i_] + bias[cf_]);  \
        }                                                                     \
    } }

    float fA[24], fB[24], fC[24];
    int ridA, ridB, ridC;
    LOADJ(fA, ridA, 0)
    if (nt > 1) LOADJ(fB, ridB, 1)
    int j = 0;
    while (true) {
        if (j + 2 < nt) LOADJ(fC, ridC, j + 2)
        COMPJ(fA, ridA, j)
        if (j + 1 >= nt) break;
        if (j + 3 < nt) LOADJ(fA, ridA, j + 3)
        COMPJ(fB, ridB, j + 1)
        if (j + 2 >= nt) break;
        if (j + 4 < nt) LOADJ(fB, ridB, j + 4)
        COMPJ(fC, ridC, j + 2)
        if (j + 3 >= nt) break;
        j += 3;
    }
#undef LOADJ
#undef COMPJ
}

extern "C" void kernel_launch(void* const* d_in, const int* in_sizes, int n_in,
                              void* d_out, int out_size, void* d_ws, size_t ws_size,
                              hipStream_t stream) {
    const float* obs         = (const float*)d_in[0];
    const float* neis        = (const float*)d_in[1];
    const int*   self_labels = (const int*)d_in[2];
    const int*   nei_labels  = (const int*)d_in[3];
    const float* modes       = (const float*)d_in[4];
    const float* obs_W       = (const float*)d_in[5];
    const float* obs_b       = (const float*)d_in[6];
    const float* nei_W       = (const float*)d_in[7];
    const float* nei_b       = (const float*)d_in[8];
    const float* mode_W      = (const float*)d_in[9];
    const float* mode_b      = (const float*)d_in[10];

    float* out0  = (float*)d_out;
    float* out_n = out0 + (size_t)BATCH * NMODES * EMBED;

    char* ws = (char*)d_ws;
    int* counts = (int*)ws;                                        // 24 B
    int* lists  = (int*)(ws + 256);                                // 3 MiB
    float* proj = (float*)(ws + 256 + (size_t)NEXP * NROWS * 4);   // 100 KiB
    unsigned short* wfrag = (unsigned short*)(ws + 256 + (size_t)NEXP * NROWS * 4
                                              + (size_t)NCLS * NMODES * EMBED * 4); // 576 KiB

    hipMemsetAsync(counts, 0, NEXP * sizeof(int), stream);

    prep_all<<<NBIN + NWF + NPRJ, 256, 0, stream>>>(nei_labels, counts, lists,
                                                    nei_W, wfrag,
                                                    modes, mode_W, mode_b, proj);
    obs_mode<<<BATCH / BPB, 256, 0, stream>>>(obs, self_labels, obs_W, obs_b,
                                              mode_W, proj, out0);
    nei_gemv_mfma<<<GRID2, 256, 0, stream>>>(neis, wfrag, nei_b,
                                             counts, lists, out_n);
}